// Round 5
// baseline (110.045 us; speedup 1.0000x reference)
//
#include <hip/hip_runtime.h>
#include <hip/hip_bf16.h>
#include <stdint.h>

#define BHn 64
#define Mn 1024
#define SPANn 1024
#define DHn 64
#define NKEY (Mn + SPANn)
#define BKn 32
#define NITER 34
#define INV32 (1.0f / 32.0f)
// 1/sqrt(512) * log2(e)  -- exp2-direct scaling
#define QSCALE 0.06376580586258808f

typedef short s16x8 __attribute__((ext_vector_type(8)));
typedef float f32x4 __attribute__((ext_vector_type(4)));

__device__ __forceinline__ short f2bf(float x) {
    union { float f; unsigned int u; } v; v.f = x;
    unsigned int u = v.u;
    unsigned int r = (u + 0x7FFFu + ((u >> 16) & 1u)) >> 16;
    return (short)r;
}
__device__ __forceinline__ float bf2f(short s) {
    union { unsigned int u; float f; } v;
    v.u = ((unsigned int)(unsigned short)s) << 16;
    return v.f;
}
__device__ __forceinline__ unsigned pack2(float a, float b) {
    __hip_bfloat162 h = __float22bfloat162_rn(float2{a, b});
    union { __hip_bfloat162 h2; unsigned u; } c; c.h2 = h;
    return c.u;
}

__device__ __forceinline__ void gload16(const void* g, void* l) {
    __builtin_amdgcn_global_load_lds(
        (const __attribute__((address_space(1))) void*)g,
        (__attribute__((address_space(3))) void*)l, 16, 0, 0);
}

// 32 rows x 64 cols bf16 -> LDS rows of 128B; source col pre-XOR'd with
// (row&7) at 16B granule (read side XORs (row&7)<<4 bytes).
__device__ __forceinline__ void stageKP(const short* srcbase, size_t stride,
                                        short* ldsbase, int tid) {
    const int row = tid >> 3;
    const int scol = ((tid & 7) ^ (row & 7)) << 3;
    const short* src = srcbase + (size_t)row * stride + scol;
    short* dst = ldsbase + ((tid >> 6) << 9);  // wave-uniform; HW adds lane*16B
    gload16(src, dst);
}

// 64 d-rows x 32 n-cols bf16 -> LDS rows of 64B; XOR granule (row>>1)&3
// (64B rows = 16 banks, so bank spread needs row bits 1-2).
__device__ __forceinline__ void stageV(const short* vtbase, short* ldsbase, int tid) {
    const int row = tid >> 2;
    const int scol = ((tid & 3) ^ ((row >> 1) & 3)) << 3;
    const short* src = vtbase + (size_t)row * NKEY + scol;
    short* dst = ldsbase + ((tid >> 6) << 9);
    gload16(src, dst);
}

// ---------------- fused prepass: K->bf16, V->bf16 transposed, peT ----------------
__global__ void prep_kernel(const float* __restrict__ K, short* __restrict__ Kb,
                            const float* __restrict__ V, short* __restrict__ Vt,
                            const float* __restrict__ pe, short* __restrict__ peT) {
    int blk = blockIdx.x;
    if (blk < 4096) {
        size_t idx = ((size_t)blk * 256 + threadIdx.x) * 8;
        const float* p = K + idx;
        s16x8 o;
#pragma unroll
        for (int e = 0; e < 8; ++e) o[e] = f2bf(p[e]);
        *(s16x8*)(Kb + idx) = o;
    } else if (blk < 4096 + 2048) {
        __shared__ float tile[64][65];
        int t = blk - 4096;
        int b = t >> 5;
        int n0 = (t & 31) << 6;
        int r = threadIdx.x >> 2;
        int c0 = (threadIdx.x & 3) << 4;
        const float* src = V + ((size_t)b * NKEY + n0 + r) * DHn + c0;
#pragma unroll
        for (int e = 0; e < 16; ++e) tile[r][c0 + e] = src[e];
        __syncthreads();
        short* dst = Vt + ((size_t)b * DHn + r) * NKEY + n0 + c0;
#pragma unroll
        for (int e = 0; e < 16; ++e) dst[e] = f2bf(tile[c0 + e][r]);
    } else {
        int idx = (blk - 4096 - 2048) * 256 + threadIdx.x;
        int l = idx >> 6, d = idx & 63;
        peT[l * DHn + d] = f2bf(pe[d * SPANn + l]);
    }
}

// ---------------- main attention kernel ----------------
__global__ __launch_bounds__(256, 3) void attn5_kernel(
    const float* __restrict__ q, const short* __restrict__ Kb,
    const short* __restrict__ Vt, const short* __restrict__ peT,
    const float* __restrict__ cur, float* __restrict__ out) {
    __shared__ short KA[2][2048];   // 8 KB  (32 n x 64 d)
    __shared__ short VA[2][2048];   // 8 KB  (64 d x 32 n)
    __shared__ short PE[2][2048];   // 8 KB  (32 l x 64 d)
    __shared__ short P[4096];       // 8 KB: 64 q-rows x 128B
    __shared__ short Ring[8192];    // 16 KB: 64 q-rows x 128-entry bf16 pos ring

    // block order: per-XCD (g&7), one b at a time (16 consecutive m-tiles)
    const int g = blockIdx.x;
    const int b = (((g >> 7) & 7) << 3) | (g & 7);
    const int m0 = ((g >> 3) & 15) << 6;
    const int head = b & 7;
    const int tid = threadIdx.x;
    const int lane = tid & 63;
    const int w = tid >> 6;
    const int l15 = lane & 15;
    const int lh = lane >> 4;

    const float cv = cur[head];
    const float c_h = (cv * (float)SPANn - (float)(SPANn - 1)) * INV32 + 1.0f;

    const short* KbB = Kb + (size_t)b * NKEY * DHn;
    const short* VtB = Vt + (size_t)b * DHn * NKEY;

    // Q fragment (B operand), pre-scaled for exp2-direct
    s16x8 qfrag[2];
    {
        const float* qrow = q + ((size_t)b * Mn + m0 + 16 * w + l15) * DHn;
#pragma unroll
        for (int t2 = 0; t2 < 2; ++t2) {
            int d0 = 32 * t2 + 8 * lh;
#pragma unroll
            for (int e = 0; e < 8; ++e)
                qfrag[t2][e] = f2bf(qrow[d0 + e] * QSCALE);
        }
    }

    f32x4 o_acc[4];
#pragma unroll
    for (int c = 0; c < 4; ++c) o_acc[c] = (f32x4){0.f, 0.f, 0.f, 0.f};
    float zm = 0.f;

    // prologue: stage tile 0, full drain once
    stageKP(KbB + (size_t)m0 * DHn, DHn, &KA[0][0], tid);
    stageV(VtB + m0, &VA[0][0], tid);
    stageKP(peT, DHn, &PE[0][0], tid);
    __syncthreads();

    const int prow = 16 * w + l15;
    const int swp = (prow & 7) << 4;
    const int ringsw = swp;
    char* ringrow = (char*)Ring + prow * 256;
    char* prowp = (char*)P + prow * 128;

#pragma unroll 1
    for (int t = 0; t < NITER; ++t) {
        const int D = 32 * t;
        const int cb = t & 1;

        // ---- issue staging for t+1 (3 loads/wave), counted wait, barrier ----
        if (t + 1 < NITER) {
            const int n1 = m0 + D + 32;
            stageKP(KbB + (size_t)n1 * DHn, DHn, &KA[cb ^ 1][0], tid);
            stageV(VtB + n1, &VA[cb ^ 1][0], tid);
            const int pc = (t + 1 < 32) ? (D + 32) : 0;  // dummy-stage keeps count uniform
            stageKP(peT + (size_t)pc * DHn, DHn, &PE[cb ^ 1][0], tid);
            asm volatile("s_waitcnt vmcnt(3)" ::: "memory");  // tile t landed; t+1 in flight
        } else {
            asm volatile("s_waitcnt vmcnt(0)" ::: "memory");
        }
        __builtin_amdgcn_s_barrier();

        // ---- pos GEMM chunk t (l = D..D+31) -> bf16 ring (wave-private rows) ----
        if (t < 32) {
            const char* PEb = (const char*)&PE[cb][0];
#pragma unroll
            for (int c = 0; c < 2; ++c) {
                const int ar = 16 * c + l15;
                const int sw = (ar & 7) << 4;
                const char* base = PEb + ar * 128;
                s16x8 a0 = *(const s16x8*)(base + ((16 * lh) ^ sw));
                s16x8 a1 = *(const s16x8*)(base + ((64 + 16 * lh) ^ sw));
                f32x4 pa = (f32x4){0.f, 0.f, 0.f, 0.f};
                pa = __builtin_amdgcn_mfma_f32_16x16x32_bf16(a0, qfrag[0], pa, 0, 0, 0);
                pa = __builtin_amdgcn_mfma_f32_16x16x32_bf16(a1, qfrag[1], pa, 0, 0, 0);
                const int idx0 = (D + 16 * c + 4 * lh) & 127;
                uint2 pk = {pack2(pa[0], pa[1]), pack2(pa[2], pa[3])};
                *(uint2*)(ringrow + (((idx0 << 1) ^ ringsw))) = pk;
            }
        }

        // ---- S^T = K Q (+ ring pos), exp2, span mask -> P ----
        {
            const char* Kbf = (const char*)&KA[cb][0];
#pragma unroll
            for (int c = 0; c < 2; ++c) {
                const int lbc = D + 16 * c - 16 * w;  // wave-uniform
                const int lmin = lbc - 15, lmax = lbc + 15;
                char* pdst = prowp + ((32 * c + 8 * lh) ^ swp);
                if ((lmax < 0) | (lmin > 1023) |
                    (c_h + (float)lmax * INV32 <= 0.0f)) {
                    *(uint2*)pdst = (uint2){0u, 0u};
                    continue;
                }
                const int ar = 16 * c + l15;
                const int sw = (ar & 7) << 4;
                const char* base = Kbf + ar * 128;
                s16x8 a0 = *(const s16x8*)(base + ((16 * lh) ^ sw));
                s16x8 a1 = *(const s16x8*)(base + ((64 + 16 * lh) ^ sw));
                f32x4 sa = (f32x4){0.f, 0.f, 0.f, 0.f};
                sa = __builtin_amdgcn_mfma_f32_16x16x32_bf16(a0, qfrag[0], sa, 0, 0, 0);
                sa = __builtin_amdgcn_mfma_f32_16x16x32_bf16(a1, qfrag[1], sa, 0, 0, 0);
                const int lb = lbc + 4 * lh - l15;
                float pm[4];
                if ((lmin >= 0) && (lmax <= 1023) &&
                    (c_h + (float)lmin * INV32 >= 1.0f)) {
                    // FAST: mask==1, all l valid
#pragma unroll
                    for (int r = 0; r < 4; ++r) {
                        float pos = bf2f(*(const short*)(
                            ringrow + ((((lb + r) & 127) << 1) ^ ringsw)));
                        pm[r] = __builtin_amdgcn_exp2f(sa[r] + pos);
                        zm += pm[r];
                    }
                } else {
                    // SLOW: band edge and/or ramp
#pragma unroll
                    for (int r = 0; r < 4; ++r) {
                        int l = lb + r;
                        float pos = bf2f(*(const short*)(
                            ringrow + (((l & 127) << 1) ^ ringsw)));
                        float p = __builtin_amdgcn_exp2f(sa[r] + pos);
                        p = ((unsigned)l < 1024u) ? p : 0.0f;
                        float mk = fminf(fmaxf((float)l * INV32 + c_h, 0.0f), 1.0f);
                        pm[r] = p * mk;
                        zm += pm[r];
                    }
                }
                *(uint2*)pdst = (uint2){pack2(pm[0], pm[1]), pack2(pm[2], pm[3])};
            }
        }

        // ---- PV: O += P * V (wave-private P; 1 A-frag, 4 MFMA) ----
        {
            s16x8 pf = *(const s16x8*)(prowp + ((16 * lh) ^ swp));
            const char* Vbf = (const char*)&VA[cb][0];
            __builtin_amdgcn_s_setprio(1);
#pragma unroll
            for (int c = 0; c < 4; ++c) {
                const int vr = 16 * c + l15;
                const int swv = ((vr >> 1) & 3) << 4;
                s16x8 v = *(const s16x8*)(Vbf + vr * 64 + ((16 * lh) ^ swv));
                o_acc[c] = __builtin_amdgcn_mfma_f32_16x16x32_bf16(pf, v, o_acc[c], 0, 0, 0);
            }
            __builtin_amdgcn_s_setprio(0);
        }

        // all LDS reads of buf t done before next iter's staging can overwrite
        asm volatile("s_waitcnt lgkmcnt(0)" ::: "memory");
        __builtin_amdgcn_s_barrier();
    }

    // ---- zm reduction across lh groups (cols already lane-local) ----
    zm += __shfl_xor(zm, 16, 64);
    zm += __shfl_xor(zm, 32, 64);

    // ---- epilogue: out = O / zm ----
#pragma unroll
    for (int r = 0; r < 4; ++r) {
        float zmr = __shfl(zm, 4 * lh + r, 64);
        float dn = 1.0f / (zmr + 1e-20f);
        float* orow = out + ((size_t)b * Mn + m0 + 16 * w + 4 * lh + r) * DHn;
#pragma unroll
        for (int c = 0; c < 4; ++c)
            orow[16 * c + l15] = o_acc[c][r] * dn;
    }
}

extern "C" void kernel_launch(void* const* d_in, const int* in_sizes, int n_in,
                              void* d_out, int out_size, void* d_ws, size_t ws_size,
                              hipStream_t stream) {
    (void)in_sizes; (void)n_in; (void)out_size; (void)ws_size;
    const float* q = (const float*)d_in[0];
    const float* key = (const float*)d_in[1];
    const float* val = (const float*)d_in[2];
    const float* pe = (const float*)d_in[3];
    const float* cur = (const float*)d_in[4];
    float* out = (float*)d_out;

    const size_t KV_ELEMS = (size_t)BHn * NKEY * DHn;  // 8,388,608
    short* Kb = (short*)d_ws;
    short* Vt = Kb + KV_ELEMS;
    short* peT = Vt + KV_ELEMS;

    prep_kernel<<<4096 + 2048 + 256, 256, 0, stream>>>(key, Kb, val, Vt, pe, peT);
    attn5_kernel<<<64 * (Mn / 64), 256, 0, stream>>>(q, Kb, Vt, peT, cur, out);
}

// Round 6
// 90.122 us; speedup vs baseline: 1.2211x; 1.2211x over previous
//
#include <hip/hip_runtime.h>
#include <hip/hip_bf16.h>
#include <stdint.h>

#define BHn 64
#define Mn 1024
#define SPANn 1024
#define DHn 64
#define NKEY (Mn + SPANn)
#define NITER 34
#define INV32 (1.0f / 32.0f)
// 1/sqrt(512) * log2(e)  -- exp2-direct scaling
#define QSCALE 0.06376580586258808f

typedef short s16x8 __attribute__((ext_vector_type(8)));
typedef float f32x4 __attribute__((ext_vector_type(4)));

__device__ __forceinline__ short f2bf(float x) {
    union { float f; unsigned int u; } v; v.f = x;
    unsigned int u = v.u;
    unsigned int r = (u + 0x7FFFu + ((u >> 16) & 1u)) >> 16;
    return (short)r;
}
__device__ __forceinline__ float bf2f(short s) {
    union { unsigned int u; float f; } v;
    v.u = ((unsigned int)(unsigned short)s) << 16;
    return v.f;
}
__device__ __forceinline__ unsigned pack2(float a, float b) {
    __hip_bfloat162 h = __float22bfloat162_rn(float2{a, b});
    union { __hip_bfloat162 h2; unsigned u; } c; c.h2 = h;
    return c.u;
}

__device__ __forceinline__ void gload16(const void* g, void* l) {
    __builtin_amdgcn_global_load_lds(
        (const __attribute__((address_space(1))) void*)g,
        (__attribute__((address_space(3))) void*)l, 16, 0, 0);
}

// 32 rows x 64 cols bf16 -> LDS rows of 128B; source col pre-XOR'd with
// (row&7) at 16B granule (read side XORs (row&7)<<4 bytes).
__device__ __forceinline__ void stageKP(const short* srcbase, size_t stride,
                                        short* ldsbase, int tid) {
    const int row = tid >> 3;
    const int scol = ((tid & 7) ^ (row & 7)) << 3;
    const short* src = srcbase + (size_t)row * stride + scol;
    short* dst = ldsbase + ((tid >> 6) << 9);  // wave-uniform; HW adds lane*16B
    gload16(src, dst);
}

// 64 d-rows x 32 n-cols bf16 -> LDS rows of 64B; XOR granule (row>>1)&3.
__device__ __forceinline__ void stageV(const short* vtbase, short* ldsbase, int tid) {
    const int row = tid >> 2;
    const int scol = ((tid & 3) ^ ((row >> 1) & 3)) << 3;
    const short* src = vtbase + (size_t)row * NKEY + scol;
    short* dst = ldsbase + ((tid >> 6) << 9);
    gload16(src, dst);
}

// ---------------- fused prepass: K->bf16, V->bf16 transposed, peT ----------------
__global__ void prep_kernel(const float* __restrict__ K, short* __restrict__ Kb,
                            const float* __restrict__ V, short* __restrict__ Vt,
                            const float* __restrict__ pe, short* __restrict__ peT) {
    int blk = blockIdx.x;
    if (blk < 4096) {
        size_t idx = ((size_t)blk * 256 + threadIdx.x) * 8;
        const float* p = K + idx;
        s16x8 o;
#pragma unroll
        for (int e = 0; e < 8; ++e) o[e] = f2bf(p[e]);
        *(s16x8*)(Kb + idx) = o;
    } else if (blk < 4096 + 2048) {
        __shared__ float tile[64][65];
        int t = blk - 4096;
        int b = t >> 5;
        int n0 = (t & 31) << 6;
        int r = threadIdx.x >> 2;
        int c0 = (threadIdx.x & 3) << 4;
        const float* src = V + ((size_t)b * NKEY + n0 + r) * DHn + c0;
#pragma unroll
        for (int e = 0; e < 16; ++e) tile[r][c0 + e] = src[e];
        __syncthreads();
        short* dst = Vt + ((size_t)b * DHn + r) * NKEY + n0 + c0;
#pragma unroll
        for (int e = 0; e < 16; ++e) dst[e] = f2bf(tile[c0 + e][r]);
    } else {
        int idx = (blk - 4096 - 2048) * 256 + threadIdx.x;
        int l = idx >> 6, d = idx & 63;
        peT[l * DHn + d] = f2bf(pe[d * SPANn + l]);
    }
}

// ---------------- main attention kernel ----------------
__global__ __launch_bounds__(256, 4) void attn6_kernel(
    const float* __restrict__ q, const short* __restrict__ Kb,
    const short* __restrict__ Vt, const short* __restrict__ peT,
    const float* __restrict__ cur, float* __restrict__ out) {
    __shared__ short KA[2][2048];   // 8 KB  (32 n x 64 d)
    __shared__ short VA[2][2048];   // 8 KB  (64 d x 32 n)
    __shared__ short PE[2][2048];   // 8 KB  (32 l x 64 d)
    __shared__ short Ring[8192];    // 16 KB: 64 q-rows x 128-entry bf16 pos ring
                                    // total 40 KB -> 4 blocks/CU

    const int g = blockIdx.x;
    const int b = g & 63;           // g%8==b%8 -> per-b XCD locality (R4 order)
    const int m0 = (g >> 6) << 6;
    const int head = b & 7;
    const int tid = threadIdx.x;
    const int lane = tid & 63;
    const int w = tid >> 6;
    const int l15 = lane & 15;
    const int lh = lane >> 4;

    const float cv = cur[head];
    const float c_h = (cv * (float)SPANn - (float)(SPANn - 1)) * INV32 + 1.0f;

    const short* KbB = Kb + (size_t)b * NKEY * DHn;
    const short* VtB = Vt + (size_t)b * DHn * NKEY;

    // Q fragment (B operand), pre-scaled for exp2-direct
    s16x8 qfrag[2];
    {
        const float* qrow = q + ((size_t)b * Mn + m0 + 16 * w + l15) * DHn;
#pragma unroll
        for (int t2 = 0; t2 < 2; ++t2) {
            int d0 = 32 * t2 + 8 * lh;
#pragma unroll
            for (int e = 0; e < 8; ++e)
                qfrag[t2][e] = f2bf(qrow[d0 + e] * QSCALE);
        }
    }

    f32x4 o_acc[4];
#pragma unroll
    for (int c = 0; c < 4; ++c) o_acc[c] = (f32x4){0.f, 0.f, 0.f, 0.f};
    float zm = 0.f;

    const int prow = 16 * w + l15;
    const int ringsw = (prow & 7) << 4;
    char* ringrow = (char*)Ring + prow * 256;

    // ---- prologue: stage K/V tile0, PE chunks 0 and 1 ----
    stageKP(KbB + (size_t)m0 * DHn, DHn, &KA[0][0], tid);
    stageV(VtB + m0, &VA[0][0], tid);
    stageKP(peT, DHn, &PE[0][0], tid);
    stageKP(peT + (size_t)32 * DHn, DHn, &PE[1][0], tid);
    __syncthreads();

    // pre-loop pos GEMM: chunk 0 (l = 0..31) from PE[0] -> ring (wave-private)
    {
        const char* PEb = (const char*)&PE[0][0];
#pragma unroll
        for (int c = 0; c < 2; ++c) {
            const int ar = 16 * c + l15;
            const int sw = (ar & 7) << 4;
            const char* base = PEb + ar * 128;
            s16x8 a0 = *(const s16x8*)(base + ((16 * lh) ^ sw));
            s16x8 a1 = *(const s16x8*)(base + ((64 + 16 * lh) ^ sw));
            f32x4 pa = (f32x4){0.f, 0.f, 0.f, 0.f};
            pa = __builtin_amdgcn_mfma_f32_16x16x32_bf16(a0, qfrag[0], pa, 0, 0, 0);
            pa = __builtin_amdgcn_mfma_f32_16x16x32_bf16(a1, qfrag[1], pa, 0, 0, 0);
            const int idx0 = 16 * c + 4 * lh;  // chunk 0
            uint2 pk = {pack2(pa[0], pa[1]), pack2(pa[2], pa[3])};
            *(uint2*)(ringrow + ((idx0 << 1) ^ ringsw)) = pk;
        }
    }
    __syncthreads();  // PE[0] readers done before iter0 re-stages it

#pragma unroll 1
    for (int t = 0; t < NITER; ++t) {
        const int D = 32 * t;
        const int cb = t & 1;

        // ---- issue staging for t+1 (K/V) and PE chunk t+2 ----
        if (t + 1 < NITER) {
            const int n1 = m0 + D + 32;
            stageKP(KbB + (size_t)n1 * DHn, DHn, &KA[cb ^ 1][0], tid);
            stageV(VtB + n1, &VA[cb ^ 1][0], tid);
        }
        if (t + 2 <= 31)
            stageKP(peT + (size_t)(D + 64) * DHn, DHn, &PE[cb][0], tid);

        // ---- pos GEMM chunk t+1 (from PE[cb^1], staged last iter) ----
        if (t + 1 <= 31) {
            const char* PEb = (const char*)&PE[cb ^ 1][0];
#pragma unroll
            for (int c = 0; c < 2; ++c) {
                const int ar = 16 * c + l15;
                const int sw = (ar & 7) << 4;
                const char* base = PEb + ar * 128;
                s16x8 a0 = *(const s16x8*)(base + ((16 * lh) ^ sw));
                s16x8 a1 = *(const s16x8*)(base + ((64 + 16 * lh) ^ sw));
                f32x4 pa = (f32x4){0.f, 0.f, 0.f, 0.f};
                pa = __builtin_amdgcn_mfma_f32_16x16x32_bf16(a0, qfrag[0], pa, 0, 0, 0);
                pa = __builtin_amdgcn_mfma_f32_16x16x32_bf16(a1, qfrag[1], pa, 0, 0, 0);
                const int idx0 = (D + 32 + 16 * c + 4 * lh) & 127;
                uint2 pk = {pack2(pa[0], pa[1]), pack2(pa[2], pa[3])};
                *(uint2*)(ringrow + ((idx0 << 1) ^ ringsw)) = pk;
            }
        }

        // ---- S^T = K Q (+ ring pos, lagged), exp2, span mask -> dwords ----
        unsigned sd[4];  // c0d0, c0d1, c1d0, c1d1
        bool zgrp[2];
        {
            const char* Kbf = (const char*)&KA[cb][0];
#pragma unroll
            for (int c = 0; c < 2; ++c) {
                const int lbc = D + 16 * c - 16 * w;  // wave-uniform
                const int lmin = lbc - 15, lmax = lbc + 15;
                const bool zero = (lmax < 0) | (lmin > 1023) |
                                  (c_h + (float)lmax * INV32 <= 0.0f);
                zgrp[c] = zero;
                if (zero) {
                    sd[2 * c] = 0u;
                    sd[2 * c + 1] = 0u;
                    continue;
                }
                const int ar = 16 * c + l15;
                const int sw = (ar & 7) << 4;
                const char* base = Kbf + ar * 128;
                s16x8 a0 = *(const s16x8*)(base + ((16 * lh) ^ sw));
                s16x8 a1 = *(const s16x8*)(base + ((64 + 16 * lh) ^ sw));
                f32x4 sa = (f32x4){0.f, 0.f, 0.f, 0.f};
                sa = __builtin_amdgcn_mfma_f32_16x16x32_bf16(a0, qfrag[0], sa, 0, 0, 0);
                sa = __builtin_amdgcn_mfma_f32_16x16x32_bf16(a1, qfrag[1], sa, 0, 0, 0);
                const int lb = lbc + 4 * lh - l15;
                float pm[4];
                if ((lmin >= 0) && (lmax <= 1023) &&
                    (c_h + (float)lmin * INV32 >= 1.0f)) {
                    // FAST: mask==1, all l valid
#pragma unroll
                    for (int r = 0; r < 4; ++r) {
                        float pos = bf2f(*(const short*)(
                            ringrow + ((((lb + r) & 127) << 1) ^ ringsw)));
                        pm[r] = __builtin_amdgcn_exp2f(sa[r] + pos);
                        zm += pm[r];
                    }
                } else {
                    // SLOW: band edge and/or ramp
#pragma unroll
                    for (int r = 0; r < 4; ++r) {
                        int l = lb + r;
                        float pos = bf2f(*(const short*)(
                            ringrow + (((l & 127) << 1) ^ ringsw)));
                        float p = __builtin_amdgcn_exp2f(sa[r] + pos);
                        p = ((unsigned)l < 1024u) ? p : 0.0f;
                        float mk = fminf(fmaxf((float)l * INV32 + c_h, 0.0f), 1.0f);
                        pm[r] = p * mk;
                        zm += pm[r];
                    }
                }
                sd[2 * c] = pack2(pm[0], pm[1]);
                sd[2 * c + 1] = pack2(pm[2], pm[3]);
            }
        }

        // ---- in-register transpose S^T(n,m) -> P(m,n) via ds_bpermute ----
        // target dword j: src lane 16*((2lh+(j>>1))&3)+l15, c-group lh>>1, dw j&1
        if (!(zgrp[0] && zgrp[1])) {
            const int A0 = (16 * ((2 * lh) & 3) + l15) << 2;
            const int A1 = (16 * ((2 * lh + 1) & 3) + l15) << 2;
            int t00 = __builtin_amdgcn_ds_bpermute(A0, (int)sd[0]);
            int t01 = __builtin_amdgcn_ds_bpermute(A0, (int)sd[1]);
            int t10 = __builtin_amdgcn_ds_bpermute(A1, (int)sd[0]);
            int t11 = __builtin_amdgcn_ds_bpermute(A1, (int)sd[1]);
            int u00 = __builtin_amdgcn_ds_bpermute(A0, (int)sd[2]);
            int u01 = __builtin_amdgcn_ds_bpermute(A0, (int)sd[3]);
            int u10 = __builtin_amdgcn_ds_bpermute(A1, (int)sd[2]);
            int u11 = __builtin_amdgcn_ds_bpermute(A1, (int)sd[3]);
            const bool hi = lh >= 2;
            union { int i[4]; s16x8 v; } pf;
            pf.i[0] = hi ? u00 : t00;
            pf.i[1] = hi ? u01 : t01;
            pf.i[2] = hi ? u10 : t10;
            pf.i[3] = hi ? u11 : t11;

            // ---- PV: O += P * V ----
            const char* Vbf = (const char*)&VA[cb][0];
            __builtin_amdgcn_s_setprio(1);
#pragma unroll
            for (int c = 0; c < 4; ++c) {
                const int vr = 16 * c + l15;
                const int swv = ((vr >> 1) & 3) << 4;
                s16x8 v = *(const s16x8*)(Vbf + vr * 64 + ((16 * lh) ^ swv));
                o_acc[c] = __builtin_amdgcn_mfma_f32_16x16x32_bf16(pf.v, v, o_acc[c], 0, 0, 0);
            }
            __builtin_amdgcn_s_setprio(0);
        }

        __syncthreads();  // staging landed; all waves done with current bufs
    }

    // ---- zm reduction across lh groups (cols already lane-local) ----
    zm += __shfl_xor(zm, 16, 64);
    zm += __shfl_xor(zm, 32, 64);

    // ---- epilogue: out = O / zm ----
#pragma unroll
    for (int r = 0; r < 4; ++r) {
        float zmr = __shfl(zm, 4 * lh + r, 64);
        float dn = 1.0f / (zmr + 1e-20f);
        float* orow = out + ((size_t)b * Mn + m0 + 16 * w + 4 * lh + r) * DHn;
#pragma unroll
        for (int c = 0; c < 4; ++c)
            orow[16 * c + l15] = o_acc[c][r] * dn;
    }
}

extern "C" void kernel_launch(void* const* d_in, const int* in_sizes, int n_in,
                              void* d_out, int out_size, void* d_ws, size_t ws_size,
                              hipStream_t stream) {
    (void)in_sizes; (void)n_in; (void)out_size; (void)ws_size;
    const float* q = (const float*)d_in[0];
    const float* key = (const float*)d_in[1];
    const float* val = (const float*)d_in[2];
    const float* pe = (const float*)d_in[3];
    const float* cur = (const float*)d_in[4];
    float* out = (float*)d_out;

    const size_t KV_ELEMS = (size_t)BHn * NKEY * DHn;  // 8,388,608
    short* Kb = (short*)d_ws;
    short* Vt = Kb + KV_ELEMS;
    short* peT = Vt + KV_ELEMS;

    prep_kernel<<<4096 + 2048 + 256, 256, 0, stream>>>(key, Kb, val, Vt, pe, peT);
    attn6_kernel<<<64 * (Mn / 64), 256, 0, stream>>>(q, Kb, Vt, peT, cur, out);
}